// Round 6
// baseline (642.974 us; speedup 1.0000x reference)
//
#include <hip/hip_runtime.h>

// SudokuLoss: B=65536 puzzles, G=9, C=10 classes, BS=3.
// v7: v6's persistent grid + SOFTWARE-PIPELINED rounds (T14 issue-early/
// consume-late). Main-kernel history (bench - ~238us fixed harness fills):
//   v3=128.6 (10923 WGs, LDS atomics)   v4~=114 / v5~=116 (10923-WG
//   dispatch floor ~10.4ns/WG)          v6=57 (persistent 1024 blocks).
// v6 residue: no pipe >18us (LDS ~17, VALU ~15, HBM ~15) but wall 57us --
// per-round critical path gather(900cy latency)->softmax->bar->phase2(only
// 3/8 waves)->bar serializes; barriers stop any cross-phase overlap.
// v7 reorders each round: ISSUE gathers -> phase2 on PREVIOUS round's probs
// (LDS work hides gather latency in the same waves) -> softmax -> bar ->
// LDS write -> bar. Barriers now bracket only the 30-cyc write. Same
// buffer, same LDS (24.7KB, 4 blocks/CU), same per-cell math and per-thread
// accumulation order -> bitwise-identical outputs.

constexpr int kB     = 65536;
constexpr int TPB    = 512;          // threads per block (8 waves)
constexpr int NBLK   = 1024;         // 4 blocks/CU x 256 CU: fully resident
constexpr int PPBLK  = kB / NBLK;    // 64 puzzles per block
constexpr int PPB_R  = 6;            // puzzles per round (486 cells < 512)
constexpr int ROUNDS = (PPBLK + PPB_R - 1) / PPB_R;   // 11 (last round: 4)
constexpr int NSLOT  = 256;          // global accumulation slots
constexpr int SLOT_STRIDE = 16;      // floats per slot (64B line)
constexpr int CSTRIDE = 12;          // floats per cell slot in LDS (48B)

// phase 2: one thread per (puzzle, group), group-major; returns this
// thread's diff2 contribution for the round whose probs are in LDS.
__device__ __forceinline__ float group_mse(const float* __restrict__ probs, int tid)
{
    float diff2 = 0.f;
    if (tid < PPB_R * 27) {
        float s[10];
        #pragma unroll
        for (int c = 0; c < 10; ++c) s[c] = 0.f;

        if (tid < PPB_R * 9) {                       // rows
            const int q2 = tid / 9, rr = tid - q2 * 9;
            const float* base = &probs[(q2 * 81 + rr * 9) * CSTRIDE];
            #pragma unroll
            for (int i = 0; i < 9; ++i) {
                const float* cell = base + i * CSTRIDE;
                const float4 a = *(const float4*)(cell + 0);
                const float4 b = *(const float4*)(cell + 4);
                const float2 c2 = *(const float2*)(cell + 8);
                s[0]+=a.x; s[1]+=a.y; s[2]+=a.z; s[3]+=a.w;
                s[4]+=b.x; s[5]+=b.y; s[6]+=b.z; s[7]+=b.w;
                s[8]+=c2.x; s[9]+=c2.y;
            }
        } else if (tid < PPB_R * 18) {               // cols
            const int u = tid - PPB_R * 9;
            const int q2 = u / 9, j = u - q2 * 9;
            const float* base = &probs[(q2 * 81 + j) * CSTRIDE];
            #pragma unroll
            for (int i = 0; i < 9; ++i) {
                const float* cell = base + i * (9 * CSTRIDE);
                const float4 a = *(const float4*)(cell + 0);
                const float4 b = *(const float4*)(cell + 4);
                const float2 c2 = *(const float2*)(cell + 8);
                s[0]+=a.x; s[1]+=a.y; s[2]+=a.z; s[3]+=a.w;
                s[4]+=b.x; s[5]+=b.y; s[6]+=b.z; s[7]+=b.w;
                s[8]+=c2.x; s[9]+=c2.y;
            }
        } else {                                     // boxes
            const int u = tid - PPB_R * 18;
            const int q2 = u / 9, b = u - q2 * 9;
            const int br = b / 3, bc = b - br * 3;
            const float* base = &probs[(q2 * 81 + br * 27 + bc * 3) * CSTRIDE];
            #pragma unroll
            for (int dr = 0; dr < 3; ++dr) {
                #pragma unroll
                for (int dc = 0; dc < 3; ++dc) {
                    const float* cell = base + (dr * 9 + dc) * CSTRIDE;
                    const float4 a = *(const float4*)(cell + 0);
                    const float4 bb = *(const float4*)(cell + 4);
                    const float2 c2 = *(const float2*)(cell + 8);
                    s[0]+=a.x; s[1]+=a.y; s[2]+=a.z; s[3]+=a.w;
                    s[4]+=bb.x; s[5]+=bb.y; s[6]+=bb.z; s[7]+=bb.w;
                    s[8]+=c2.x; s[9]+=c2.y;
                }
            }
        }
        const float tm = s[0] * (1.f / 9.f);
        #pragma unroll
        for (int c = 1; c < 10; ++c) { const float d = s[c] - tm; diff2 += d * d; }
    }
    return diff2;
}

__global__ __launch_bounds__(TPB, 8) void sudoku_main(
    const float* __restrict__ logits,
    const int*   __restrict__ targets,
    const int*   __restrict__ puzzles,
    float*       __restrict__ ws)   // ws: [NSLOT][16]; [0]=diff2 [1]=ce [2]=mcnt
{
    // per-cell slots: [0]=mask, [1..9]=masked softmax probs (classes 1..9)
    __shared__ __align__(16) float probs[TPB * CSTRIDE];   // 24576 B
    __shared__ float red[3][TPB / 64];

    const int  tid  = threadIdx.x;
    const int  q    = tid / 81;              // puzzle-in-round (0..6; 6=idle)
    const bool actq = (q < PPB_R);
    const size_t blkbase = (size_t)blockIdx.x * PPBLK * 81;

    float ce = 0.f, mcnt = 0.f, diff2 = 0.f;

    int pz_cur = 1;
    if (actq) pz_cur = puzzles[blkbase + tid];

    for (int r = 0; r < ROUNDS; ++r) {
        const bool act = actq && (r * PPB_R + q < PPBLK);
        const bool m   = act && (pz_cur == 0);   // ~10% of lanes

        // (1) ISSUE round-r gathers now; consumed after phase 2 below, so
        // their ~900-cycle HBM latency hides under the LDS reduction work.
        int tg = 0;
        float2 g0 = make_float2(0.f, 0.f), g1 = g0, g2 = g0, g3 = g0, g4 = g0;
        if (m) {
            const size_t idx = blkbase + (size_t)r * (PPB_R * 81) + tid;
            tg = targets[idx];
            const float* xp = logits + idx * 10;
            g0 = *(const float2*)(xp + 0);
            g1 = *(const float2*)(xp + 2);
            g2 = *(const float2*)(xp + 4);
            g3 = *(const float2*)(xp + 6);
            g4 = *(const float2*)(xp + 8);
        }
        // prefetch next round's puzzle value
        int pz_next = 1;
        if (r + 1 < ROUNDS) {
            const bool actn = actq && ((r + 1) * PPB_R + q < PPBLK);
            if (actn) pz_next = puzzles[blkbase + (size_t)(r + 1) * (PPB_R * 81) + tid];
        }

        // (2) phase 2 on PREVIOUS round's probs (skipped at r==0)
        if (r > 0) diff2 += group_mse(probs, tid);

        // (3) softmax on the (now arrived) gathered logits
        float wv[10];
        #pragma unroll
        for (int c = 0; c < 10; ++c) wv[c] = 0.f;
        if (m) {
            float x[10];
            x[0]=g0.x; x[1]=g0.y; x[2]=g1.x; x[3]=g1.y; x[4]=g2.x;
            x[5]=g2.y; x[6]=g3.x; x[7]=g3.y; x[8]=g4.x; x[9]=g4.y;
            float mx = x[0];
            #pragma unroll
            for (int c = 1; c < 10; ++c) mx = fmaxf(mx, x[c]);
            float e[10];
            float S = 0.f;
            #pragma unroll
            for (int c = 0; c < 10; ++c) { e[c] = __expf(x[c] - mx); S += e[c]; }
            const float inv = 1.0f / S;
            float xt = x[0];
            #pragma unroll
            for (int c = 1; c < 10; ++c) xt = (tg == c) ? x[c] : xt;
            ce   += mx + __logf(S) - xt;     // -log_softmax(x)[tg]
            mcnt += 1.f;
            wv[0] = 1.f;
            #pragma unroll
            for (int c = 1; c < 10; ++c) wv[c] = e[c] * inv;
        }

        // (4) barrier: phase-2 reads of old probs complete before overwrite
        __syncthreads();

        // (5) all 512 threads write their slot (zeros where unmasked):
        // stride-12 pattern -> lanes 0-7 cover all 32 banks, conflict-free
        {
            float* dst = &probs[tid * CSTRIDE];
            *(float4*)(dst + 0) = make_float4(wv[0], wv[1], wv[2], wv[3]);
            *(float4*)(dst + 4) = make_float4(wv[4], wv[5], wv[6], wv[7]);
            *(float2*)(dst + 8) = make_float2(wv[8], wv[9]);
        }
        // (6) barrier: writes visible to next round's phase 2
        __syncthreads();

        pz_cur = pz_next;
    }
    // epilogue: phase 2 for the final round
    diff2 += group_mse(probs, tid);

    // once per block: wave (64-lane) reduction, then cross-wave via LDS
    #pragma unroll
    for (int off = 32; off > 0; off >>= 1) {
        diff2 += __shfl_down(diff2, off);
        ce    += __shfl_down(ce, off);
        mcnt  += __shfl_down(mcnt, off);
    }
    const int wave = tid >> 6;
    if ((tid & 63) == 0) { red[0][wave] = diff2; red[1][wave] = ce; red[2][wave] = mcnt; }
    __syncthreads();
    if (tid == 0) {
        float d = 0.f, c2 = 0.f, m = 0.f;
        #pragma unroll
        for (int w = 0; w < TPB / 64; ++w) { d += red[0][w]; c2 += red[1][w]; m += red[2][w]; }
        float* slot = ws + (size_t)(blockIdx.x & (NSLOT - 1)) * SLOT_STRIDE;
        atomicAdd(&slot[0], d);
        atomicAdd(&slot[1], c2);
        atomicAdd(&slot[2], m);
    }
}

__global__ void sudoku_final(const float* __restrict__ ws, float* __restrict__ out)
{
    // one wave: each lane sums 4 slots, then shuffle-reduce
    const int t = threadIdx.x;
    float d = 0.f, c2 = 0.f, m = 0.f;
    for (int s = t; s < NSLOT; s += 64) {
        const float* sl = ws + (size_t)s * SLOT_STRIDE;
        d += sl[0]; c2 += sl[1]; m += sl[2];
    }
    #pragma unroll
    for (int off = 32; off > 0; off >>= 1) {
        d  += __shfl_down(d, off);
        c2 += __shfl_down(c2, off);
        m  += __shfl_down(m, off);
    }
    if (t == 0) {
        const float ce_loss = c2 / (m + 1e-8f);
        // each of row/col/box loss = sum(diff^2)/(B*9); constraint = sum/27
        const float constraint = d / ((float)kB * 9.f * 27.f);
        out[0] = ce_loss + 0.1f * constraint;
        out[1] = ce_loss;
        out[2] = constraint;
    }
}

extern "C" void kernel_launch(void* const* d_in, const int* in_sizes, int n_in,
                              void* d_out, int out_size, void* d_ws, size_t ws_size,
                              hipStream_t stream)
{
    const float* logits  = (const float*)d_in[0];
    const int*   targets = (const int*)d_in[1];
    const int*   puzzles = (const int*)d_in[2];
    float* ws  = (float*)d_ws;
    float* out = (float*)d_out;

    hipMemsetAsync(d_ws, 0, NSLOT * SLOT_STRIDE * sizeof(float), stream);

    sudoku_main<<<NBLK, TPB, 0, stream>>>(logits, targets, puzzles, ws);
    sudoku_final<<<1, 64, 0, stream>>>(ws, out);
}

// Round 8
// 350.446 us; speedup vs baseline: 1.8347x; 1.8347x over previous
//
#include <hip/hip_runtime.h>

// SudokuLoss: B=65536 puzzles, G=9, C=10 classes, BS=3.
// v8: v7's software pipeline + ENOUGH REGISTERS. History (bench - ~238us
// harness fills): v4/v5~=115 (WG dispatch floor), v6=57 (persistent 1024
// blocks, serial rounds), v7=417 REGRESSION.
// v7 post-mortem: launch_bounds(512,8) caps 64 VGPR/wave; holding the 11
// gather regs across group_mse (~25 live floats) forced scratch spills:
// VGPR_Count=32, WRITE_SIZE=721MB, FETCH=624MB (needed ~85/1) -> the kernel
// became scratch-BW-bound at 3.3TB/s. The pipeline was right; the register
// budget wasn't.
// v8: NBLK=512 (2 blocks/CU, still fully co-resident -> no dispatch floor),
// launch_bounds(512,4) -> 128 VGPR/wave -> no spills. Halved TLP is covered
// by the in-thread pipeline: round-r gathers issue before round-(r-1)'s
// phase-2 LDS reduction, hiding ~900cy HBM latency in the same waves.
// Per-cell math and accumulation order identical (absmax 0.0 throughout).
// (Round 7 bench was an infra failure -- container died before running;
// this is the same v8 source resubmitted.)

constexpr int kB     = 65536;
constexpr int TPB    = 512;          // threads per block (8 waves)
constexpr int NBLK   = 512;          // 2 blocks/CU x 256 CU: fully resident
constexpr int PPBLK  = kB / NBLK;    // 128 puzzles per block
constexpr int PPB_R  = 6;            // puzzles per round (486 cells < 512)
constexpr int ROUNDS = (PPBLK + PPB_R - 1) / PPB_R;   // 22 (last round: 2)
constexpr int NSLOT  = 256;          // global accumulation slots
constexpr int SLOT_STRIDE = 16;      // floats per slot (64B line)
constexpr int CSTRIDE = 12;          // floats per cell slot in LDS (48B)

// phase 2: one thread per (puzzle, group), group-major; returns this
// thread's diff2 contribution for the round whose probs are in LDS.
__device__ __forceinline__ float group_mse(const float* __restrict__ probs, int tid)
{
    float diff2 = 0.f;
    if (tid < PPB_R * 27) {
        float s[10];
        #pragma unroll
        for (int c = 0; c < 10; ++c) s[c] = 0.f;

        if (tid < PPB_R * 9) {                       // rows
            const int q2 = tid / 9, rr = tid - q2 * 9;
            const float* base = &probs[(q2 * 81 + rr * 9) * CSTRIDE];
            #pragma unroll
            for (int i = 0; i < 9; ++i) {
                const float* cell = base + i * CSTRIDE;
                const float4 a = *(const float4*)(cell + 0);
                const float4 b = *(const float4*)(cell + 4);
                const float2 c2 = *(const float2*)(cell + 8);
                s[0]+=a.x; s[1]+=a.y; s[2]+=a.z; s[3]+=a.w;
                s[4]+=b.x; s[5]+=b.y; s[6]+=b.z; s[7]+=b.w;
                s[8]+=c2.x; s[9]+=c2.y;
            }
        } else if (tid < PPB_R * 18) {               // cols
            const int u = tid - PPB_R * 9;
            const int q2 = u / 9, j = u - q2 * 9;
            const float* base = &probs[(q2 * 81 + j) * CSTRIDE];
            #pragma unroll
            for (int i = 0; i < 9; ++i) {
                const float* cell = base + i * (9 * CSTRIDE);
                const float4 a = *(const float4*)(cell + 0);
                const float4 b = *(const float4*)(cell + 4);
                const float2 c2 = *(const float2*)(cell + 8);
                s[0]+=a.x; s[1]+=a.y; s[2]+=a.z; s[3]+=a.w;
                s[4]+=b.x; s[5]+=b.y; s[6]+=b.z; s[7]+=b.w;
                s[8]+=c2.x; s[9]+=c2.y;
            }
        } else {                                     // boxes
            const int u = tid - PPB_R * 18;
            const int q2 = u / 9, b = u - q2 * 9;
            const int br = b / 3, bc = b - br * 3;
            const float* base = &probs[(q2 * 81 + br * 27 + bc * 3) * CSTRIDE];
            #pragma unroll
            for (int dr = 0; dr < 3; ++dr) {
                #pragma unroll
                for (int dc = 0; dc < 3; ++dc) {
                    const float* cell = base + (dr * 9 + dc) * CSTRIDE;
                    const float4 a = *(const float4*)(cell + 0);
                    const float4 bb = *(const float4*)(cell + 4);
                    const float2 c2 = *(const float2*)(cell + 8);
                    s[0]+=a.x; s[1]+=a.y; s[2]+=a.z; s[3]+=a.w;
                    s[4]+=bb.x; s[5]+=bb.y; s[6]+=bb.z; s[7]+=bb.w;
                    s[8]+=c2.x; s[9]+=c2.y;
                }
            }
        }
        const float tm = s[0] * (1.f / 9.f);
        #pragma unroll
        for (int c = 1; c < 10; ++c) { const float d = s[c] - tm; diff2 += d * d; }
    }
    return diff2;
}

__global__ __launch_bounds__(TPB, 4) void sudoku_main(
    const float* __restrict__ logits,
    const int*   __restrict__ targets,
    const int*   __restrict__ puzzles,
    float*       __restrict__ ws)   // ws: [NSLOT][16]; [0]=diff2 [1]=ce [2]=mcnt
{
    // per-cell slots: [0]=mask, [1..9]=masked softmax probs (classes 1..9)
    __shared__ __align__(16) float probs[TPB * CSTRIDE];   // 24576 B
    __shared__ float red[3][TPB / 64];

    const int  tid  = threadIdx.x;
    const int  q    = tid / 81;              // puzzle-in-round (0..6; 6=idle)
    const bool actq = (q < PPB_R);
    const size_t blkbase = (size_t)blockIdx.x * PPBLK * 81;

    float ce = 0.f, mcnt = 0.f, diff2 = 0.f;

    int pz_cur = 1;
    if (actq) pz_cur = puzzles[blkbase + tid];

    for (int r = 0; r < ROUNDS; ++r) {
        const bool act = actq && (r * PPB_R + q < PPBLK);
        const bool m   = act && (pz_cur == 0);   // ~10% of lanes

        // (1) ISSUE round-r gathers now; consumed after phase 2 below, so
        // their ~900-cycle HBM latency hides under the LDS reduction work.
        int tg = 0;
        float2 g0 = make_float2(0.f, 0.f), g1 = g0, g2 = g0, g3 = g0, g4 = g0;
        if (m) {
            const size_t idx = blkbase + (size_t)r * (PPB_R * 81) + tid;
            tg = targets[idx];
            const float* xp = logits + idx * 10;
            g0 = *(const float2*)(xp + 0);
            g1 = *(const float2*)(xp + 2);
            g2 = *(const float2*)(xp + 4);
            g3 = *(const float2*)(xp + 6);
            g4 = *(const float2*)(xp + 8);
        }
        // prefetch next round's puzzle value
        int pz_next = 1;
        if (r + 1 < ROUNDS) {
            const bool actn = actq && ((r + 1) * PPB_R + q < PPBLK);
            if (actn) pz_next = puzzles[blkbase + (size_t)(r + 1) * (PPB_R * 81) + tid];
        }

        // (2) phase 2 on PREVIOUS round's probs (skipped at r==0)
        if (r > 0) diff2 += group_mse(probs, tid);

        // (3) softmax on the (now arrived) gathered logits
        float wv[10];
        #pragma unroll
        for (int c = 0; c < 10; ++c) wv[c] = 0.f;
        if (m) {
            float x[10];
            x[0]=g0.x; x[1]=g0.y; x[2]=g1.x; x[3]=g1.y; x[4]=g2.x;
            x[5]=g2.y; x[6]=g3.x; x[7]=g3.y; x[8]=g4.x; x[9]=g4.y;
            float mx = x[0];
            #pragma unroll
            for (int c = 1; c < 10; ++c) mx = fmaxf(mx, x[c]);
            float e[10];
            float S = 0.f;
            #pragma unroll
            for (int c = 0; c < 10; ++c) { e[c] = __expf(x[c] - mx); S += e[c]; }
            const float inv = 1.0f / S;
            float xt = x[0];
            #pragma unroll
            for (int c = 1; c < 10; ++c) xt = (tg == c) ? x[c] : xt;
            ce   += mx + __logf(S) - xt;     // -log_softmax(x)[tg]
            mcnt += 1.f;
            wv[0] = 1.f;
            #pragma unroll
            for (int c = 1; c < 10; ++c) wv[c] = e[c] * inv;
        }

        // (4) barrier: phase-2 reads of old probs complete before overwrite
        __syncthreads();

        // (5) all 512 threads write their slot (zeros where unmasked)
        {
            float* dst = &probs[tid * CSTRIDE];
            *(float4*)(dst + 0) = make_float4(wv[0], wv[1], wv[2], wv[3]);
            *(float4*)(dst + 4) = make_float4(wv[4], wv[5], wv[6], wv[7]);
            *(float2*)(dst + 8) = make_float2(wv[8], wv[9]);
        }
        // (6) barrier: writes visible to next round's phase 2
        __syncthreads();

        pz_cur = pz_next;
    }
    // epilogue: phase 2 for the final round
    diff2 += group_mse(probs, tid);

    // once per block: wave (64-lane) reduction, then cross-wave via LDS
    #pragma unroll
    for (int off = 32; off > 0; off >>= 1) {
        diff2 += __shfl_down(diff2, off);
        ce    += __shfl_down(ce, off);
        mcnt  += __shfl_down(mcnt, off);
    }
    const int wave = tid >> 6;
    if ((tid & 63) == 0) { red[0][wave] = diff2; red[1][wave] = ce; red[2][wave] = mcnt; }
    __syncthreads();
    if (tid == 0) {
        float d = 0.f, c2 = 0.f, m = 0.f;
        #pragma unroll
        for (int w = 0; w < TPB / 64; ++w) { d += red[0][w]; c2 += red[1][w]; m += red[2][w]; }
        float* slot = ws + (size_t)(blockIdx.x & (NSLOT - 1)) * SLOT_STRIDE;
        atomicAdd(&slot[0], d);
        atomicAdd(&slot[1], c2);
        atomicAdd(&slot[2], m);
    }
}

__global__ void sudoku_final(const float* __restrict__ ws, float* __restrict__ out)
{
    // one wave: each lane sums 4 slots, then shuffle-reduce
    const int t = threadIdx.x;
    float d = 0.f, c2 = 0.f, m = 0.f;
    for (int s = t; s < NSLOT; s += 64) {
        const float* sl = ws + (size_t)s * SLOT_STRIDE;
        d += sl[0]; c2 += sl[1]; m += sl[2];
    }
    #pragma unroll
    for (int off = 32; off > 0; off >>= 1) {
        d  += __shfl_down(d, off);
        c2 += __shfl_down(c2, off);
        m  += __shfl_down(m, off);
    }
    if (t == 0) {
        const float ce_loss = c2 / (m + 1e-8f);
        // each of row/col/box loss = sum(diff^2)/(B*9); constraint = sum/27
        const float constraint = d / ((float)kB * 9.f * 27.f);
        out[0] = ce_loss + 0.1f * constraint;
        out[1] = ce_loss;
        out[2] = constraint;
    }
}

extern "C" void kernel_launch(void* const* d_in, const int* in_sizes, int n_in,
                              void* d_out, int out_size, void* d_ws, size_t ws_size,
                              hipStream_t stream)
{
    const float* logits  = (const float*)d_in[0];
    const int*   targets = (const int*)d_in[1];
    const int*   puzzles = (const int*)d_in[2];
    float* ws  = (float*)d_ws;
    float* out = (float*)d_out;

    hipMemsetAsync(d_ws, 0, NSLOT * SLOT_STRIDE * sizeof(float), stream);

    sudoku_main<<<NBLK, TPB, 0, stream>>>(logits, targets, puzzles, ws);
    sudoku_final<<<1, 64, 0, stream>>>(ws, out);
}